// Round 13
// baseline (1636.039 us; speedup 1.0000x reference)
//
#include <hip/hip_runtime.h>

// ---------------------------------------------------------------------------
// BiSSM global block, MI355X — round 13: levels at wave-tile 64x128 (4-wave
// 128x256 blocks, 2-buf stage-early), k_uz + slim k_fin2 retained.
//   u[t]=xn@Bm^T (dup), z[t]=xn@gw^T                         k_uz
//   X_2k[t] = X_k[t] + X_k[t-/+k]@(A^k)^T, k=1..512          k_lvl x10
//   Xsum[t] = X_f[t]+X_f[t-1024]@W + X_b[t]+X_b[t+1024]@W    k_cmb (W=A^1024)
//   out     = x + alpha*0.5*(Xsum@Cm^T)*sigmoid(z+gb)        k_fin2
// k_lvl: 128x256 tile, BK=32, 256 thr (4 waves 2x2, wave=64x128 ->
// 12 ds_read : 32 MFMA per wave-step), 2-buf LDS 48KB (2-3 blocks/CU),
// stage-early + ONE __syncthreads per K-step (round-6 proven). glds16 with
// chunk swizzle c^((r^(r>>2))&3) both sides. Epilogue: 4 phases of 32x256
// f32 LDS bounce (stride BLS) -> vectorized res-add + global I/O.
// Powers A^2..A^1024: hi/lo-bf16 f32 squaring chain (k_sq x10, 3-pass).
// ---------------------------------------------------------------------------

typedef short  bfrag __attribute__((ext_vector_type(8)));   // 8 x bf16
typedef float  ffrag __attribute__((ext_vector_type(4)));   // mfma acc
typedef float  f4    __attribute__((ext_vector_type(4)));
typedef short  s4v   __attribute__((ext_vector_type(4)));   // 4 x bf16

#define DEV static __device__ __forceinline__
#define Hn 768
#define FLS 132   // 128+4 pad (f32 bounce stride, 128-wide tiles)
#define BLS 260   // 256+4 pad (f32 bounce stride, 256-wide tiles)

DEV unsigned short f2bf(float f) {
  unsigned u = __float_as_uint(f);
  u += 0x7fffu + ((u >> 16) & 1u);            // round-to-nearest-even
  return (unsigned short)(u >> 16);
}
DEV float bf2f(unsigned short s) { return __uint_as_float(((unsigned)s) << 16); }

DEV ffrag mfma16(bfrag a, bfrag b, ffrag c) {
  return __builtin_amdgcn_mfma_f32_16x16x32_bf16(a, b, c, 0, 0, 0);
}

DEV void glds16(const unsigned short* g, unsigned short* l) {
  __builtin_amdgcn_global_load_lds(
      (const __attribute__((address_space(1))) unsigned int*)g,
      (__attribute__((address_space(3))) unsigned int*)l, 16, 0, 0);
}

union BF8 { bfrag v; unsigned short u[8]; };

// ---------------------------------------------------------------------------
// k_abuild: gridDim = (768, 4); task = blockIdx.y
__global__ __launch_bounds__(256) void k_abuild(
    const float* __restrict__ U, const float* __restrict__ V,
    const float* __restrict__ S, const float* __restrict__ Bm,
    const float* __restrict__ Cm, const float* __restrict__ gw,
    float* __restrict__ Af, float* __restrict__ AfT,
    unsigned short* __restrict__ Abf,
    unsigned short* __restrict__ Bmb, unsigned short* __restrict__ Cmb,
    unsigned short* __restrict__ gwb, unsigned short* __restrict__ zp) {
  int i = blockIdx.x;
  int task = blockIdx.y;
  if (task == 0) {
    float u0 = U[i*4+0], u1 = U[i*4+1], u2 = U[i*4+2], u3 = U[i*4+3];
    for (int j = threadIdx.x; j < Hn; j += 256) {
      float a = u0*V[j*4+0] + u1*V[j*4+1] + u2*V[j*4+2] + u3*V[j*4+3]
              + S[i*Hn+j] - S[j*Hn+i];
      if (i == j) a += -(float)(i+1) / 768.0f;
      Af[i*Hn+j]  = a;
      AfT[j*Hn+i] = a;
      Abf[i*Hn+j] = f2bf(a);
    }
    if (i == 0) for (int j = threadIdx.x; j < 1024; j += 256) zp[j] = 0;
  } else {
    const float* src = (task==1) ? Bm : (task==2) ? Cm : gw;
    unsigned short* dst = (task==1) ? Bmb : (task==2) ? Cmb : gwb;
    for (int j = threadIdx.x; j < Hn; j += 256) dst[i*Hn+j] = f2bf(src[i*Hn+j]);
  }
}

// ---------------------------------------------------------------------------
// k_rms: one wave per row (row = b*2048 + t); write xn in (t,b) order, bf16.
__global__ __launch_bounds__(256) void k_rms(
    const float* __restrict__ x, const float* __restrict__ scale,
    unsigned short* __restrict__ xn) {
  int row  = blockIdx.x * 4 + (threadIdx.x >> 6);
  int lane = threadIdx.x & 63;
  int b = row >> 11, t = row & 2047;
  const float* xr = x + (long)row * Hn;
  float v[12];
  float ss = 0.f;
#pragma unroll
  for (int j = 0; j < 12; ++j) { v[j] = xr[lane + j*64]; ss += v[j]*v[j]; }
#pragma unroll
  for (int off = 1; off < 64; off <<= 1) ss += __shfl_xor(ss, off);
  float inv = 1.0f / sqrtf(ss / 768.0f + 1e-8f);
  unsigned short* dst = xn + ((long)t * 8 + b) * Hn;
#pragma unroll
  for (int j = 0; j < 12; ++j) dst[lane + j*64] = f2bf(v[j] * inv * scale[lane + j*64]);
}

// ---------------------------------------------------------------------------
// k_sq: Z = X @ X, hi/lo bf16 (3 passes). Writes Z rm + Z^T rm f32 + bf16.
// grid (12, 6), 512 thr, tile 64x128.
__global__ __launch_bounds__(512) void k_sq(
    const float* __restrict__ X, const float* __restrict__ XT,
    float* __restrict__ Z, float* __restrict__ ZT,
    unsigned short* __restrict__ Zbf) {
  int tid = threadIdx.x, lane = tid & 63, w = tid >> 6;
  int mw = w >> 2, nw = w & 3, l15 = lane & 15, lhi = lane >> 4;
  int rb = blockIdx.x * 64, cb = blockIdx.y * 128;
  ffrag acc[2][2] = {};
  for (int kt = 0; kt < 24; ++kt) {
    int k0 = kt*32 + lhi*8;
    BF8 ah[2], al[2], bh[2], bl[2];
#pragma unroll
    for (int mt = 0; mt < 2; ++mt) {
      const f4* p = (const f4*)(X + (long)(rb + mw*32 + mt*16 + l15) * Hn + k0);
      f4 x0 = p[0], x1 = p[1];
#pragma unroll
      for (int j = 0; j < 8; ++j) {
        float f = (j < 4) ? x0[j] : x1[j-4];
        unsigned short h = f2bf(f);
        ah[mt].u[j] = h; al[mt].u[j] = f2bf(f - bf2f(h));
      }
    }
#pragma unroll
    for (int nt = 0; nt < 2; ++nt) {
      const f4* p = (const f4*)(XT + (long)(cb + nw*32 + nt*16 + l15) * Hn + k0);
      f4 x0 = p[0], x1 = p[1];
#pragma unroll
      for (int j = 0; j < 8; ++j) {
        float f = (j < 4) ? x0[j] : x1[j-4];
        unsigned short h = f2bf(f);
        bh[nt].u[j] = h; bl[nt].u[j] = f2bf(f - bf2f(h));
      }
    }
#pragma unroll
    for (int mt = 0; mt < 2; ++mt)
#pragma unroll
      for (int nt = 0; nt < 2; ++nt) {
        acc[mt][nt] = mfma16(ah[mt].v, bh[nt].v, acc[mt][nt]);
        acc[mt][nt] = mfma16(ah[mt].v, bl[nt].v, acc[mt][nt]);
        acc[mt][nt] = mfma16(al[mt].v, bh[nt].v, acc[mt][nt]);
      }
  }
#pragma unroll
  for (int mt = 0; mt < 2; ++mt)
#pragma unroll
    for (int nt = 0; nt < 2; ++nt)
#pragma unroll
      for (int q = 0; q < 4; ++q) {
        int grow = rb + mw*32 + mt*16 + lhi*4 + q;
        int gcol = cb + nw*32 + nt*16 + l15;
        float vv = acc[mt][nt][q];
        Z[(long)grow*Hn + gcol] = vv;
        ZT[(long)gcol*Hn + grow] = vv;
        Zbf[(long)grow*Hn + gcol] = f2bf(vv);
      }
}

// ---------------------------------------------------------------------------
// k_lvl: 128x256 tile, BK=32, 24 K-steps, 256 thr (4 waves 2x2, wave tile
// 64x128 -> 12 ds_read : 32 MFMA). 2-buf LDS (48KB), stage-early, ONE
// __syncthreads per step. out = res + A0[row -/+ sh] @ B0^T. grid 768.
__global__ __launch_bounds__(256) void k_lvl(
    const unsigned short* __restrict__ A0s, const unsigned short* __restrict__ B0s,
    const unsigned short* __restrict__ res, unsigned short* __restrict__ outb,
    const unsigned short* __restrict__ zp, int sh) {
  constexpr int BUFS = 4096 + 8192;                // shorts: A 8KB + B 16KB
  __shared__ __align__(16) unsigned short ldsb[2 * BUFS];   // 48 KB

  const int tid = threadIdx.x, lane = tid & 63, w = tid >> 6;
  const int l15 = lane & 15, lhi = lane >> 4;
  const int wr = w >> 1, wc = w & 1;               // 2 x 2 wave grid

  // XCD-aware bijective block swizzle (m204), col-fast decompose (ncol=3).
  const int nwg = gridDim.x;
  const int q8 = nwg >> 3, r8 = nwg & 7, xcd = blockIdx.x & 7, fo = blockIdx.x >> 3;
  const int wg = (xcd < r8 ? xcd*(q8+1) : r8*(q8+1) + (xcd - r8)*q8) + fo;
  const int cb = wg % 3, rbk = wg / 3;
  const long r0  = (long)rbk * 128;
  const long bc0 = (long)cb * 256;
  const int dir = (r0 >= 16384) ? 1 : 0;
  const bool skip = dir ? (r0 >= 32768 - sh) : (r0 + 128 <= sh);

  // staging: lane rowin = lane>>2, chunk ch = lane&3; src chunk = ch ^ XS.
  // A: 2 insts/wave (rows inst*16..+15 of 128); B: 4 insts/wave (of 256).
  const int rowin = lane >> 2, ch = lane & 3;
  const int cswz = ch ^ ((rowin ^ (rowin >> 2)) & 3);   // row%16 == rowin
  long gA[2]; bool vA[2]; int lA[2];
#pragma unroll
  for (int jj = 0; jj < 2; ++jj) {
    const int rl = (w*2 + jj)*16 + rowin;
    long gr = r0 + rl + (dir ? sh : -sh);
    vA[jj] = dir ? (gr < 32768) : (gr >= 0);
    gA[jj] = gr * Hn + cswz*8;
    lA[jj] = (w*2 + jj) * 512;
  }
  long gB[4]; int lB[4];
#pragma unroll
  for (int jj = 0; jj < 4; ++jj) {
    const int rl = (w*4 + jj)*16 + rowin;
    gB[jj] = (bc0 + rl) * Hn + cswz*8;
    lB[jj] = 4096 + (w*4 + jj) * 512;
  }

  auto stage = [&](int buf, int kt) {
    const int ko = kt * 32;
    unsigned short* dst = ldsb + buf * BUFS;
#pragma unroll
    for (int jj = 0; jj < 2; ++jj) {
      const unsigned short* g = vA[jj] ? (A0s + gA[jj] + ko) : zp;
      glds16(g, dst + lA[jj]);
    }
#pragma unroll
    for (int jj = 0; jj < 4; ++jj)
      glds16(B0s + gB[jj] + ko, dst + lB[jj]);
  };

  ffrag acc[4][8] = {};
  const int cx = (lhi ^ ((l15 ^ (l15 >> 2)) & 3)) * 8;   // swizzled read chunk

  if (!skip) {
    stage(0, 0);
    __syncthreads();
    int cur = 0;
    for (int kt = 0; kt < 24; ++kt) {
      if (kt < 23) stage(cur ^ 1, kt + 1);   // issue next tile BEFORE compute
      const unsigned short* L = ldsb + cur * BUFS;
      bfrag a[4], b[8];
#pragma unroll
      for (int mt = 0; mt < 4; ++mt)
        a[mt] = *(const bfrag*)&L[(wr*64 + mt*16 + l15)*32 + cx];
#pragma unroll
      for (int nt = 0; nt < 8; ++nt)
        b[nt] = *(const bfrag*)&L[4096 + (wc*128 + nt*16 + l15)*32 + cx];
#pragma unroll
      for (int mt = 0; mt < 4; ++mt)
#pragma unroll
        for (int nt = 0; nt < 8; ++nt)
          acc[mt][nt] = mfma16(a[mt], b[nt], acc[mt][nt]);
      __syncthreads();                       // staged tile ready; reads done
      cur ^= 1;
    }
  }

  // ---- epilogue: 4 phases; phase p bounces acc[p] (32 rows x 256 f32) ----
  float* fl = (float*)ldsb;                  // 32 x BLS f32 = 33280 B <= 48K
#pragma unroll
  for (int p = 0; p < 4; ++p) {
    __syncthreads();
#pragma unroll
    for (int nt = 0; nt < 8; ++nt)
#pragma unroll
      for (int q = 0; q < 4; ++q)
        fl[(wr*16 + lhi*4 + q)*BLS + wc*128 + nt*16 + l15] = acc[p][nt][q];
    __syncthreads();
    for (int i = tid; i < 2048; i += 256) {
      const int srow = i >> 6;               // 0..31
      const int cc   = (i & 63) << 2;        // 0..252
      f4 v = *(const f4*)&fl[srow*BLS + cc];
      const long grow = r0 + (srow >> 4)*64 + p*16 + (srow & 15);
      const long gcol = bc0 + cc;
      const long go = grow * Hn + gcol;
      s4v rv = *(const s4v*)&res[go];
#pragma unroll
      for (int j = 0; j < 4; ++j) v[j] += bf2f(((unsigned short*)&rv)[j]);
      s4v ov;
#pragma unroll
      for (int j = 0; j < 4; ++j) ((unsigned short*)&ov)[j] = f2bf(v[j]);
      *(s4v*)&outb[go] = ov;
    }
  }
}

// ---------------------------------------------------------------------------
// k_cmb: combine (round-10 proven structure). 128x256 tile, 8 waves 2x4,
// 2-buf, stage-early, one barrier/step. grid 384.
// out = res[r]+res[r+16384] + (A0[r-sh]+A0[r+16384+sh]) @ B0^T
__global__ __launch_bounds__(512) void k_cmb(
    const unsigned short* __restrict__ A0s, const unsigned short* __restrict__ B0s,
    const unsigned short* __restrict__ res, unsigned short* __restrict__ outb,
    const unsigned short* __restrict__ zp, int sh) {
  constexpr int BUFS = 2 * 4096 + 8192;
  __shared__ __align__(16) unsigned short ldsb[2 * BUFS];

  const int tid = threadIdx.x, lane = tid & 63, w = tid >> 6;
  const int l15 = lane & 15, lhi = lane >> 4;
  const int wr = w >> 2, wc = w & 3;

  const int nwg = gridDim.x;
  const int q8 = nwg >> 3, r8 = nwg & 7, xcd = blockIdx.x & 7, fo = blockIdx.x >> 3;
  const int wg = (xcd < r8 ? xcd*(q8+1) : r8*(q8+1) + (xcd - r8)*q8) + fo;
  const int cb = wg % 3, rbk = wg / 3;
  const long r0  = (long)rbk * 128;
  const long bc0 = (long)cb * 256;

  const int rowin = lane >> 2, ch = lane & 3;
  const int rA = w*16 + rowin;
  const int cswz = ch ^ ((rowin ^ (rowin >> 2)) & 3);
  long gA[2]; bool vA[2];
  { long g0 = r0 + rA - sh;         vA[0] = (g0 >= 0);    gA[0] = g0 * Hn + cswz*8; }
  { long g1 = r0 + rA + 16384 + sh; vA[1] = (g1 < 32768); gA[1] = g1 * Hn + cswz*8; }
  long gB[2];
#pragma unroll
  for (int j = 0; j < 2; ++j)
    gB[j] = (bc0 + j*128 + rA) * Hn + cswz*8;

  auto stage = [&](int buf, int kt) {
    const int ko = kt * 32;
    unsigned short* dst = ldsb + buf * BUFS;
#pragma unroll
    for (int s = 0; s < 2; ++s) {
      const unsigned short* g = vA[s] ? (A0s + gA[s] + ko) : zp;
      glds16(g, dst + s*4096 + w*512);
    }
#pragma unroll
    for (int j = 0; j < 2; ++j)
      glds16(B0s + gB[j] + ko, dst + 2*4096 + j*4096 + w*512);
  };

  ffrag acc[4][4] = {};
  const int cx = (lhi ^ ((l15 ^ (l15 >> 2)) & 3)) * 8;

  stage(0, 0);
  __syncthreads();
  int cur = 0;
  for (int kt = 0; kt < 24; ++kt) {
    if (kt < 23) stage(cur ^ 1, kt + 1);
    const unsigned short* L = ldsb + cur * BUFS;
    bfrag a[2][4], b[4];
#pragma unroll
    for (int mt = 0; mt < 4; ++mt) {
      const int row = wr*64 + mt*16 + l15;
      a[0][mt] = *(const bfrag*)&L[row*32 + cx];
      a[1][mt] = *(const bfrag*)&L[4096 + row*32 + cx];
    }
#pragma unroll
    for (int nt = 0; nt < 4; ++nt) {
      const int row = wc*64 + nt*16 + l15;
      b[nt] = *(const bfrag*)&L[2*4096 + row*32 + cx];
    }
#pragma unroll
    for (int mt = 0; mt < 4; ++mt)
#pragma unroll
      for (int nt = 0; nt < 4; ++nt) {
        acc[mt][nt] = mfma16(a[0][mt], b[nt], acc[mt][nt]);
        acc[mt][nt] = mfma16(a[1][mt], b[nt], acc[mt][nt]);
      }
    __syncthreads();
    cur ^= 1;
  }

  float* fl = (float*)ldsb;
#pragma unroll
  for (int p = 0; p < 4; ++p) {
    __syncthreads();
#pragma unroll
    for (int nt = 0; nt < 4; ++nt)
#pragma unroll
      for (int q = 0; q < 4; ++q)
        fl[(wr*16 + lhi*4 + q)*BLS + wc*64 + nt*16 + l15] = acc[p][nt][q];
    __syncthreads();
    for (int i = tid; i < 2048; i += 512) {
      const int srow = i >> 6;
      const int cc   = (i & 63) << 2;
      f4 v = *(const f4*)&fl[srow*BLS + cc];
      const long grow = r0 + (srow >> 4)*64 + p*16 + (srow & 15);
      const long gcol = bc0 + cc;
      const long go = grow * Hn + gcol;
      s4v ra = *(const s4v*)&res[go];
      s4v rb2 = *(const s4v*)&res[go + (long)16384*Hn];
#pragma unroll
      for (int j = 0; j < 4; ++j)
        v[j] += bf2f(((unsigned short*)&ra)[j]) + bf2f(((unsigned short*)&rb2)[j]);
      s4v ov;
#pragma unroll
      for (int j = 0; j < 4; ++j) ((unsigned short*)&ov)[j] = f2bf(v[j]);
      *(s4v*)&outb[go] = ov;
    }
  }
}

// ---------------------------------------------------------------------------
// k_uz: u = xn@Bm^T (dup both halves) AND z = xn@gw^T. 128x128 tile, 4 waves,
// 2-buf (A=xn, B0=Bm, B1=gw staged; 48KB). Round-8 proven ordering. grid 768.
__global__ __launch_bounds__(256) void k_uz(
    const unsigned short* __restrict__ xn, const unsigned short* __restrict__ Bmb,
    const unsigned short* __restrict__ gwb,
    unsigned short* __restrict__ u, unsigned short* __restrict__ z) {
  __shared__ __align__(16) unsigned short ldsb[2 * 3 * 4096];

  const int tid = threadIdx.x, lane = tid & 63, w = tid >> 6;
  const int l15 = lane & 15, lhi = lane >> 4;
  const int wr = w >> 1, wc = w & 1;

  const int nwg = gridDim.x;
  const int q8 = nwg >> 3, r8 = nwg & 7, xcd = blockIdx.x & 7, fo = blockIdx.x >> 3;
  const int wg = (xcd < r8 ? xcd*(q8+1) : r8*(q8+1) + (xcd - r8)*q8) + fo;
  const int cb = wg % 6, rbk = wg / 6;
  const long r0 = (long)rbk * 128;
  const long bc0 = (long)cb * 128;

  const int rowin = lane >> 2, ch = lane & 3;
  long gA[2]; long gB[2]; int lbase[2];
#pragma unroll
  for (int jj = 0; jj < 2; ++jj) {
    const int inst = w*2 + jj;
    const int r = inst*16 + rowin;
    const int c = ch ^ ((r ^ (r >> 2)) & 3);
    lbase[jj] = inst * 512;
    gA[jj] = (r0 + r) * Hn + c*8;
    gB[jj] = (bc0 + r) * Hn + c*8;
  }

  auto stage = [&](int buf, int kt) {
    const int ko = kt * 32;
    unsigned short* dst = ldsb + buf * 12288;
#pragma unroll
    for (int jj = 0; jj < 2; ++jj) {
      glds16(xn  + gA[jj] + ko, dst + 0*4096 + lbase[jj]);
      glds16(Bmb + gB[jj] + ko, dst + 1*4096 + lbase[jj]);
      glds16(gwb + gB[jj] + ko, dst + 2*4096 + lbase[jj]);
    }
  };

  ffrag acc[4][4] = {};
  ffrag accZ[4][4] = {};
  const int cx = (lhi ^ ((l15 ^ (l15 >> 2)) & 3)) * 8;

  stage(0, 0);
  __syncthreads();
  int cur = 0;
  for (int kt = 0; kt < 24; ++kt) {
    if (kt < 23) stage(cur ^ 1, kt + 1);
    const unsigned short* L = ldsb + cur * 12288;
    bfrag a[4], b0[4], b1[4];
#pragma unroll
    for (int mt = 0; mt < 4; ++mt)
      a[mt] = *(const bfrag*)&L[(wr*64 + mt*16 + l15)*32 + cx];
#pragma unroll
    for (int nt = 0; nt < 4; ++nt) {
      const int row = wc*64 + nt*16 + l15;
      b0[nt] = *(const bfrag*)&L[1*4096 + row*32 + cx];
      b1[nt] = *(const bfrag*)&L[2*4096 + row*32 + cx];
    }
#pragma unroll
    for (int mt = 0; mt < 4; ++mt)
#pragma unroll
      for (int nt = 0; nt < 4; ++nt) {
        acc[mt][nt]  = mfma16(a[mt], b0[nt], acc[mt][nt]);
        accZ[mt][nt] = mfma16(a[mt], b1[nt], accZ[mt][nt]);
      }
    __syncthreads();
    cur ^= 1;
  }

  float* fl = (float*)ldsb;
#pragma unroll
  for (int which = 0; which < 2; ++which) {
#pragma unroll
    for (int hh = 0; hh < 2; ++hh) {
      __syncthreads();
      if (wr == hh) {
#pragma unroll
        for (int mt = 0; mt < 4; ++mt)
#pragma unroll
          for (int nt = 0; nt < 4; ++nt)
#pragma unroll
            for (int q = 0; q < 4; ++q)
              fl[(mt*16 + lhi*4 + q)*FLS + wc*64 + nt*16 + l15] =
                  which ? accZ[mt][nt][q] : acc[mt][nt][q];
      }
      __syncthreads();
      for (int i = tid; i < 2048; i += 256) {
        const int row = i >> 5;
        const int cc  = (i & 31) << 2;
        f4 v = *(const f4*)&fl[row*FLS + cc];
        const long go = (r0 + hh*64 + row) * Hn + bc0 + cc;
        s4v ov;
#pragma unroll
        for (int j = 0; j < 4; ++j) ((unsigned short*)&ov)[j] = f2bf(v[j]);
        if (which == 0) {
          *(s4v*)&u[go] = ov;
          *(s4v*)&u[go + (long)16384*Hn] = ov;
        } else {
          *(s4v*)&z[go] = ov;
        }
      }
    }
  }
}

// ---------------------------------------------------------------------------
// k_fin2: out = x + alpha*0.5*(Xsum@Cm^T)*sigmoid(z+gb). 128x128 tile,
// 4 waves, 2-buf (A=Xsum, B=Cm staged; 32KB) — smem 34048B so the 64xFLS
// f32 epilogue bounce (33792B) fits.
__global__ __launch_bounds__(256) void k_fin2(
    const unsigned short* __restrict__ A0s, const unsigned short* __restrict__ B0s,
    const unsigned short* __restrict__ z,
    const float* __restrict__ gb, const float* __restrict__ alpha,
    const float* __restrict__ x, float* __restrict__ outf) {
  __shared__ __align__(16) char smem[34048];   // max(staging 32768, bounce 33792)
  unsigned short* ldsb = (unsigned short*)smem;

  const int tid = threadIdx.x, lane = tid & 63, w = tid >> 6;
  const int l15 = lane & 15, lhi = lane >> 4;
  const int wr = w >> 1, wc = w & 1;

  const int nwg = gridDim.x;
  const int q8 = nwg >> 3, r8 = nwg & 7, xcd = blockIdx.x & 7, fo = blockIdx.x >> 3;
  const int wg = (xcd < r8 ? xcd*(q8+1) : r8*(q8+1) + (xcd - r8)*q8) + fo;
  const int cb = wg % 6, rbk = wg / 6;
  const long r0 = (long)rbk * 128;
  const long bc0 = (long)cb * 128;

  const int rowin = lane >> 2, ch = lane & 3;
  long gA[2]; long gB[2]; int lbase[2];
#pragma unroll
  for (int jj = 0; jj < 2; ++jj) {
    const int inst = w*2 + jj;
    const int r = inst*16 + rowin;
    const int c = ch ^ ((r ^ (r >> 2)) & 3);
    lbase[jj] = inst * 512;
    gA[jj] = (r0 + r) * Hn + c*8;
    gB[jj] = (bc0 + r) * Hn + c*8;
  }

  auto stage = [&](int buf, int kt) {
    const int ko = kt * 32;
    unsigned short* dst = ldsb + buf * 8192;
#pragma unroll
    for (int jj = 0; jj < 2; ++jj) {
      glds16(A0s + gA[jj] + ko, dst + lbase[jj]);
      glds16(B0s + gB[jj] + ko, dst + 4096 + lbase[jj]);
    }
  };

  ffrag acc[4][4] = {};
  const int cx = (lhi ^ ((l15 ^ (l15 >> 2)) & 3)) * 8;

  stage(0, 0);
  __syncthreads();
  int cur = 0;
  for (int kt = 0; kt < 24; ++kt) {
    if (kt < 23) stage(cur ^ 1, kt + 1);
    const unsigned short* L = ldsb + cur * 8192;
    bfrag a[4], b[4];
#pragma unroll
    for (int mt = 0; mt < 4; ++mt)
      a[mt] = *(const bfrag*)&L[(wr*64 + mt*16 + l15)*32 + cx];
#pragma unroll
    for (int nt = 0; nt < 4; ++nt)
      b[nt] = *(const bfrag*)&L[4096 + (wc*64 + nt*16 + l15)*32 + cx];
#pragma unroll
    for (int mt = 0; mt < 4; ++mt)
#pragma unroll
      for (int nt = 0; nt < 4; ++nt)
        acc[mt][nt] = mfma16(a[mt], b[nt], acc[mt][nt]);
    __syncthreads();
    cur ^= 1;
  }

  const float al = alpha[0];
  float* fl = (float*)smem;
#pragma unroll
  for (int hh = 0; hh < 2; ++hh) {
    __syncthreads();
    if (wr == hh) {
#pragma unroll
      for (int mt = 0; mt < 4; ++mt)
#pragma unroll
        for (int nt = 0; nt < 4; ++nt)
#pragma unroll
          for (int q = 0; q < 4; ++q)
            fl[(mt*16 + lhi*4 + q)*FLS + wc*64 + nt*16 + l15] = acc[mt][nt][q];
    }
    __syncthreads();
    for (int i = tid; i < 2048; i += 256) {
      const int row = i >> 5;
      const int cc  = (i & 31) << 2;
      f4 v = *(const f4*)&fl[row*FLS + cc];
      const long grow = r0 + hh*64 + row;
      const long gcol = bc0 + cc;
      const long go = grow * Hn + gcol;
      s4v zv = *(const s4v*)&z[go];
      f4 gbv = *(const f4*)&gb[gcol];
      const long t = grow >> 3, b = grow & 7;
      const long o = (b*2048 + t)*Hn + gcol;
      f4 xv = *(const f4*)&x[o];
      f4 ov;
#pragma unroll
      for (int j = 0; j < 4; ++j) {
        float zz = bf2f(((unsigned short*)&zv)[j]) + gbv[j];
        float g = 1.0f / (1.0f + __expf(-zz));
        ov[j] = xv[j] + al * 0.5f * v[j] * g;
      }
      *(f4*)&outf[o] = ov;
    }
  }
}

// ---------------------------------------------------------------------------
extern "C" void kernel_launch(void* const* d_in, const int* in_sizes, int n_in,
                              void* d_out, int out_size, void* d_ws, size_t ws_size,
                              hipStream_t stream) {
  const float* x     = (const float*)d_in[0];
  const float* scale = (const float*)d_in[1];
  const float* U     = (const float*)d_in[2];
  const float* V     = (const float*)d_in[3];
  const float* S     = (const float*)d_in[4];
  const float* Bm    = (const float*)d_in[5];
  const float* Cm    = (const float*)d_in[6];
  const float* gw    = (const float*)d_in[7];
  const float* gb    = (const float*)d_in[8];
  const float* alpha = (const float*)d_in[9];
  float* out = (float*)d_out;

  char* p = (char*)d_ws;
  auto alloc = [&](size_t sz) { char* r = p; p += (sz + 255) & ~(size_t)255; return r; };

  const size_t SZ_X  = (size_t)32768 * Hn * sizeof(unsigned short);  // 50.3MB
  const size_t SZ_BF = (size_t)16384 * Hn * sizeof(unsigned short);  // 25.2MB
  const size_t SZ_M  = (size_t)Hn * Hn * sizeof(float);              // 2.36MB
  const size_t SZ_MB = (size_t)Hn * Hn * sizeof(unsigned short);     // 1.18MB

  unsigned short* xn   = (unsigned short*)alloc(SZ_BF);
  unsigned short* zbuf = (unsigned short*)alloc(SZ_BF);
  unsigned short* XA = (unsigned short*)alloc(SZ_X);
  unsigned short* XB = (unsigned short*)alloc(SZ_X);
  float* Af  = (float*)alloc(SZ_M);
  float* AfT = (float*)alloc(SZ_M);
  float* P1  = (float*)alloc(SZ_M);
  float* P1T = (float*)alloc(SZ_M);
  float* P2  = (float*)alloc(SZ_M);
  float* P2T = (float*)alloc(SZ_M);
  unsigned short* Abf = (unsigned short*)alloc(SZ_MB);
  unsigned short* Ab[10];                      // A^2..A^1024 bf16
  for (int i = 0; i < 10; ++i) Ab[i] = (unsigned short*)alloc(SZ_MB);
  unsigned short* Bmb = (unsigned short*)alloc(SZ_MB);
  unsigned short* Cmb = (unsigned short*)alloc(SZ_MB);
  unsigned short* gwb = (unsigned short*)alloc(SZ_MB);
  unsigned short* zp  = (unsigned short*)alloc(1024 * sizeof(unsigned short));

  if ((size_t)(p - (char*)d_ws) > ws_size) return;  // workspace too small

  k_abuild<<<dim3(768, 4), 256, 0, stream>>>(U, V, S, Bm, Cm, gw,
      Af, AfT, Abf, Bmb, Cmb, gwb, zp);
  k_rms<<<4096, 256, 0, stream>>>(x, scale, xn);

  // squaring chain: A -> A^2 -> ... -> A^1024 (bf16 emitted each step)
  const float* sx = Af; const float* sxt = AfT;
  float* za = P1; float* zat = P1T; float* zb = P2; float* zbt = P2T;
  for (int i = 0; i < 10; ++i) {
    k_sq<<<dim3(12, 6), 512, 0, stream>>>(sx, sxt, za, zat, Ab[i]);
    sx = za; sxt = zat;
    float* t1 = za; float* t2 = zat; za = zb; zat = zbt; zb = t1; zbt = t2;
  }

  // u = xn@Bm^T (dup) + z = xn@gw^T
  k_uz<<<768, 256, 0, stream>>>(xn, Bmb, gwb, XA, zbuf);

  // doubling levels k=1..512 (shift sh=8k rows)
  unsigned short* src = XA; unsigned short* dst = XB;
  for (int i = 0; i < 10; ++i) {
    const unsigned short* W = (i == 0) ? Abf : Ab[i-1];
    k_lvl<<<768, 256, 0, stream>>>(src, W, src, dst, zp, 8 << i);
    unsigned short* t = src; src = dst; dst = t;
  }
  // src = XA holds X_1024 (both dirs). Combine (k=1024) + fwd/bwd sum -> XB:
  k_cmb<<<384, 512, 0, stream>>>(src, Ab[9], src, XB, zp, 8192);

  // out = x + alpha*0.5*(Xsum@Cm^T)*sigmoid(z+gb)
  k_fin2<<<768, 256, 0, stream>>>(XB, Cmb, zbuf, gb, alpha, x, out);
}

// Round 14
// 1277.829 us; speedup vs baseline: 1.2803x; 1.2803x over previous
//
#include <hip/hip_runtime.h>

// ---------------------------------------------------------------------------
// BiSSM global block, MI355X — round 14: proven-best recombination.
//   u[t]=xn@Bm^T (dup), z[t]=xn@gw^T                         k_uz   (r12, 86us)
//   X_2k[t] = X_k[t] + X_k[t-/+k]@(A^k)^T, k=1..512          k_lvl x10 (r6 best)
//   Xsum[t] = X_f[t]+X_f[t-1024]@W + X_b[t]+X_b[t+1024]@W    k_cmb (W=A^1024)
//   out     = x + alpha*0.5*(Xsum@Cm^T)*sigmoid(z+gb)        k_fin2
// k_lvl: round-6 exact structure (128x128 tile, BK=32, 4 waves 2x2, 2-buf
// 32KB stage-early, ONE __syncthreads/step, glds16 chunk swizzle
// c^((r^(r>>2))&3)) + NEW 4-phase FLS-padded epilogue bounce (16.9KB fits in
// the 32KB staging buffer -> conflict-free AND 5 blocks/CU, fixing round-6's
// 5.4M-conflict unpadded bounce). k_fin2 gets the same 4-phase bounce @32KB.
// Powers A^2..A^1024: hi/lo-bf16 f32 squaring chain (k_sq x10, 3-pass).
// ---------------------------------------------------------------------------

typedef short  bfrag __attribute__((ext_vector_type(8)));   // 8 x bf16
typedef float  ffrag __attribute__((ext_vector_type(4)));   // mfma acc
typedef float  f4    __attribute__((ext_vector_type(4)));
typedef short  s4v   __attribute__((ext_vector_type(4)));   // 4 x bf16

#define DEV static __device__ __forceinline__
#define Hn 768
#define FLS 132   // 128+4 pad (f32 bounce stride, 128-wide tiles)
#define BLS 260   // 256+4 pad (f32 bounce stride, 256-wide tiles)

DEV unsigned short f2bf(float f) {
  unsigned u = __float_as_uint(f);
  u += 0x7fffu + ((u >> 16) & 1u);            // round-to-nearest-even
  return (unsigned short)(u >> 16);
}
DEV float bf2f(unsigned short s) { return __uint_as_float(((unsigned)s) << 16); }

DEV ffrag mfma16(bfrag a, bfrag b, ffrag c) {
  return __builtin_amdgcn_mfma_f32_16x16x32_bf16(a, b, c, 0, 0, 0);
}

DEV void glds16(const unsigned short* g, unsigned short* l) {
  __builtin_amdgcn_global_load_lds(
      (const __attribute__((address_space(1))) unsigned int*)g,
      (__attribute__((address_space(3))) unsigned int*)l, 16, 0, 0);
}

union BF8 { bfrag v; unsigned short u[8]; };

// ---------------------------------------------------------------------------
// k_abuild: gridDim = (768, 4); task = blockIdx.y
__global__ __launch_bounds__(256) void k_abuild(
    const float* __restrict__ U, const float* __restrict__ V,
    const float* __restrict__ S, const float* __restrict__ Bm,
    const float* __restrict__ Cm, const float* __restrict__ gw,
    float* __restrict__ Af, float* __restrict__ AfT,
    unsigned short* __restrict__ Abf,
    unsigned short* __restrict__ Bmb, unsigned short* __restrict__ Cmb,
    unsigned short* __restrict__ gwb, unsigned short* __restrict__ zp) {
  int i = blockIdx.x;
  int task = blockIdx.y;
  if (task == 0) {
    float u0 = U[i*4+0], u1 = U[i*4+1], u2 = U[i*4+2], u3 = U[i*4+3];
    for (int j = threadIdx.x; j < Hn; j += 256) {
      float a = u0*V[j*4+0] + u1*V[j*4+1] + u2*V[j*4+2] + u3*V[j*4+3]
              + S[i*Hn+j] - S[j*Hn+i];
      if (i == j) a += -(float)(i+1) / 768.0f;
      Af[i*Hn+j]  = a;
      AfT[j*Hn+i] = a;
      Abf[i*Hn+j] = f2bf(a);
    }
    if (i == 0) for (int j = threadIdx.x; j < 1024; j += 256) zp[j] = 0;
  } else {
    const float* src = (task==1) ? Bm : (task==2) ? Cm : gw;
    unsigned short* dst = (task==1) ? Bmb : (task==2) ? Cmb : gwb;
    for (int j = threadIdx.x; j < Hn; j += 256) dst[i*Hn+j] = f2bf(src[i*Hn+j]);
  }
}

// ---------------------------------------------------------------------------
// k_rms: one wave per row (row = b*2048 + t); write xn in (t,b) order, bf16.
__global__ __launch_bounds__(256) void k_rms(
    const float* __restrict__ x, const float* __restrict__ scale,
    unsigned short* __restrict__ xn) {
  int row  = blockIdx.x * 4 + (threadIdx.x >> 6);
  int lane = threadIdx.x & 63;
  int b = row >> 11, t = row & 2047;
  const float* xr = x + (long)row * Hn;
  float v[12];
  float ss = 0.f;
#pragma unroll
  for (int j = 0; j < 12; ++j) { v[j] = xr[lane + j*64]; ss += v[j]*v[j]; }
#pragma unroll
  for (int off = 1; off < 64; off <<= 1) ss += __shfl_xor(ss, off);
  float inv = 1.0f / sqrtf(ss / 768.0f + 1e-8f);
  unsigned short* dst = xn + ((long)t * 8 + b) * Hn;
#pragma unroll
  for (int j = 0; j < 12; ++j) dst[lane + j*64] = f2bf(v[j] * inv * scale[lane + j*64]);
}

// ---------------------------------------------------------------------------
// k_sq: Z = X @ X, hi/lo bf16 (3 passes). Writes Z rm + Z^T rm f32 + bf16.
// grid (12, 6), 512 thr, tile 64x128.
__global__ __launch_bounds__(512) void k_sq(
    const float* __restrict__ X, const float* __restrict__ XT,
    float* __restrict__ Z, float* __restrict__ ZT,
    unsigned short* __restrict__ Zbf) {
  int tid = threadIdx.x, lane = tid & 63, w = tid >> 6;
  int mw = w >> 2, nw = w & 3, l15 = lane & 15, lhi = lane >> 4;
  int rb = blockIdx.x * 64, cb = blockIdx.y * 128;
  ffrag acc[2][2] = {};
  for (int kt = 0; kt < 24; ++kt) {
    int k0 = kt*32 + lhi*8;
    BF8 ah[2], al[2], bh[2], bl[2];
#pragma unroll
    for (int mt = 0; mt < 2; ++mt) {
      const f4* p = (const f4*)(X + (long)(rb + mw*32 + mt*16 + l15) * Hn + k0);
      f4 x0 = p[0], x1 = p[1];
#pragma unroll
      for (int j = 0; j < 8; ++j) {
        float f = (j < 4) ? x0[j] : x1[j-4];
        unsigned short h = f2bf(f);
        ah[mt].u[j] = h; al[mt].u[j] = f2bf(f - bf2f(h));
      }
    }
#pragma unroll
    for (int nt = 0; nt < 2; ++nt) {
      const f4* p = (const f4*)(XT + (long)(cb + nw*32 + nt*16 + l15) * Hn + k0);
      f4 x0 = p[0], x1 = p[1];
#pragma unroll
      for (int j = 0; j < 8; ++j) {
        float f = (j < 4) ? x0[j] : x1[j-4];
        unsigned short h = f2bf(f);
        bh[nt].u[j] = h; bl[nt].u[j] = f2bf(f - bf2f(h));
      }
    }
#pragma unroll
    for (int mt = 0; mt < 2; ++mt)
#pragma unroll
      for (int nt = 0; nt < 2; ++nt) {
        acc[mt][nt] = mfma16(ah[mt].v, bh[nt].v, acc[mt][nt]);
        acc[mt][nt] = mfma16(ah[mt].v, bl[nt].v, acc[mt][nt]);
        acc[mt][nt] = mfma16(al[mt].v, bh[nt].v, acc[mt][nt]);
      }
  }
#pragma unroll
  for (int mt = 0; mt < 2; ++mt)
#pragma unroll
    for (int nt = 0; nt < 2; ++nt)
#pragma unroll
      for (int q = 0; q < 4; ++q) {
        int grow = rb + mw*32 + mt*16 + lhi*4 + q;
        int gcol = cb + nw*32 + nt*16 + l15;
        float vv = acc[mt][nt][q];
        Z[(long)grow*Hn + gcol] = vv;
        ZT[(long)gcol*Hn + grow] = vv;
        Zbf[(long)grow*Hn + gcol] = f2bf(vv);
      }
}

// ---------------------------------------------------------------------------
// k_lvl: round-6 exact core. 128x128 tile, BK=32, 24 K-steps, 256 thr
// (4 waves 2x2, wave 64x64). 2-buf 32KB LDS, stage-early, ONE barrier/step.
// out = res + A0[row -/+ sh] @ B0^T. Epilogue: 4 phases x 32 rows, FLS pad
// (16.9KB <= 32KB -> conflict-free, keeps 5 blocks/CU). grid 1536.
__global__ __launch_bounds__(256) void k_lvl(
    const unsigned short* __restrict__ A0s, const unsigned short* __restrict__ B0s,
    const unsigned short* __restrict__ res, unsigned short* __restrict__ outb,
    const unsigned short* __restrict__ zp, int sh) {
  __shared__ __align__(16) unsigned short ldsb[2 * 8192];   // 32 KB

  const int tid = threadIdx.x, lane = tid & 63, w = tid >> 6;
  const int l15 = lane & 15, lhi = lane >> 4;
  const int wr = w >> 1, wc = w & 1;

  // XCD-aware bijective block swizzle (m204), col-fast decompose (ncol=6).
  const int nwg = gridDim.x;
  const int q8 = nwg >> 3, r8 = nwg & 7, xcd = blockIdx.x & 7, fo = blockIdx.x >> 3;
  const int wg = (xcd < r8 ? xcd*(q8+1) : r8*(q8+1) + (xcd - r8)*q8) + fo;
  const int cb = wg % 6, rbk = wg / 6;
  const long r0  = (long)rbk * 128;
  const long bc0 = (long)cb * 128;
  const int dir = (r0 >= 16384) ? 1 : 0;
  const bool skip = dir ? (r0 >= 32768 - sh) : (r0 + 128 <= sh);

  const int rowin = lane >> 2, ch = lane & 3;
  long gA[2]; bool vA[2]; long gB[2]; int lbase[2];
#pragma unroll
  for (int jj = 0; jj < 2; ++jj) {
    const int inst = w*2 + jj;
    const int r = inst*16 + rowin;
    const int c = ch ^ ((r ^ (r >> 2)) & 3);
    lbase[jj] = inst * 512;
    long gr = r0 + r + (dir ? sh : -sh);
    vA[jj] = dir ? (gr < 32768) : (gr >= 0);
    gA[jj] = gr * Hn + c*8;
    gB[jj] = (bc0 + r) * Hn + c*8;
  }

  auto stage = [&](int buf, int kt) {
    const int ko = kt * 32;
    unsigned short* dst = ldsb + buf * 8192;
#pragma unroll
    for (int jj = 0; jj < 2; ++jj) {
      const unsigned short* g = vA[jj] ? (A0s + gA[jj] + ko) : zp;
      glds16(g, dst + lbase[jj]);
      glds16(B0s + gB[jj] + ko, dst + 4096 + lbase[jj]);
    }
  };

  ffrag acc[4][4] = {};
  const int cx = (lhi ^ ((l15 ^ (l15 >> 2)) & 3)) * 8;   // swizzled read chunk

  if (!skip) {
    stage(0, 0);
    __syncthreads();
    int cur = 0;
    for (int kt = 0; kt < 24; ++kt) {
      if (kt < 23) stage(cur ^ 1, kt + 1);   // issue next tile BEFORE compute
      const unsigned short* L = ldsb + cur * 8192;
      bfrag a[4], b[4];
#pragma unroll
      for (int mt = 0; mt < 4; ++mt)
        a[mt] = *(const bfrag*)&L[(wr*64 + mt*16 + l15)*32 + cx];
#pragma unroll
      for (int nt = 0; nt < 4; ++nt)
        b[nt] = *(const bfrag*)&L[4096 + (wc*64 + nt*16 + l15)*32 + cx];
#pragma unroll
      for (int mt = 0; mt < 4; ++mt)
#pragma unroll
        for (int nt = 0; nt < 4; ++nt)
          acc[mt][nt] = mfma16(a[mt], b[nt], acc[mt][nt]);
      __syncthreads();                       // staged tile ready; reads done
      cur ^= 1;
    }
  }

  // ---- epilogue: 4 phases x 32 rows; FLS-padded bounce (16896B) ----
  float* fl = (float*)ldsb;
#pragma unroll
  for (int p = 0; p < 4; ++p) {
    __syncthreads();
    if (wr == (p >> 1)) {
#pragma unroll
      for (int mt2 = 0; mt2 < 2; ++mt2) {
        const int mt = (p & 1)*2 + mt2;
#pragma unroll
        for (int nt = 0; nt < 4; ++nt)
#pragma unroll
          for (int q = 0; q < 4; ++q)
            fl[(mt2*16 + lhi*4 + q)*FLS + wc*64 + nt*16 + l15] = acc[mt][nt][q];
      }
    }
    __syncthreads();
    for (int i = tid; i < 1024; i += 256) {
      const int row = i >> 5;                // 0..31
      const int cc  = (i & 31) << 2;         // 0..124
      f4 v = *(const f4*)&fl[row*FLS + cc];
      const long grow = r0 + p*32 + row;
      const long gcol = bc0 + cc;
      const long go = grow * Hn + gcol;
      s4v rv = *(const s4v*)&res[go];
#pragma unroll
      for (int j = 0; j < 4; ++j) v[j] += bf2f(((unsigned short*)&rv)[j]);
      s4v ov;
#pragma unroll
      for (int j = 0; j < 4; ++j) ((unsigned short*)&ov)[j] = f2bf(v[j]);
      *(s4v*)&outb[go] = ov;
    }
  }
}

// ---------------------------------------------------------------------------
// k_cmb: combine (round-10/12 proven). 128x256 tile, 8 waves 2x4, 2-buf,
// stage-early, one barrier/step. grid 384.
// out = res[r]+res[r+16384] + (A0[r-sh]+A0[r+16384+sh]) @ B0^T
__global__ __launch_bounds__(512) void k_cmb(
    const unsigned short* __restrict__ A0s, const unsigned short* __restrict__ B0s,
    const unsigned short* __restrict__ res, unsigned short* __restrict__ outb,
    const unsigned short* __restrict__ zp, int sh) {
  constexpr int BUFS = 2 * 4096 + 8192;
  __shared__ __align__(16) unsigned short ldsb[2 * BUFS];

  const int tid = threadIdx.x, lane = tid & 63, w = tid >> 6;
  const int l15 = lane & 15, lhi = lane >> 4;
  const int wr = w >> 2, wc = w & 3;

  const int nwg = gridDim.x;
  const int q8 = nwg >> 3, r8 = nwg & 7, xcd = blockIdx.x & 7, fo = blockIdx.x >> 3;
  const int wg = (xcd < r8 ? xcd*(q8+1) : r8*(q8+1) + (xcd - r8)*q8) + fo;
  const int cb = wg % 3, rbk = wg / 3;
  const long r0  = (long)rbk * 128;
  const long bc0 = (long)cb * 256;

  const int rowin = lane >> 2, ch = lane & 3;
  const int rA = w*16 + rowin;
  const int cswz = ch ^ ((rowin ^ (rowin >> 2)) & 3);
  long gA[2]; bool vA[2];
  { long g0 = r0 + rA - sh;         vA[0] = (g0 >= 0);    gA[0] = g0 * Hn + cswz*8; }
  { long g1 = r0 + rA + 16384 + sh; vA[1] = (g1 < 32768); gA[1] = g1 * Hn + cswz*8; }
  long gB[2];
#pragma unroll
  for (int j = 0; j < 2; ++j)
    gB[j] = (bc0 + j*128 + rA) * Hn + cswz*8;

  auto stage = [&](int buf, int kt) {
    const int ko = kt * 32;
    unsigned short* dst = ldsb + buf * BUFS;
#pragma unroll
    for (int s = 0; s < 2; ++s) {
      const unsigned short* g = vA[s] ? (A0s + gA[s] + ko) : zp;
      glds16(g, dst + s*4096 + w*512);
    }
#pragma unroll
    for (int j = 0; j < 2; ++j)
      glds16(B0s + gB[j] + ko, dst + 2*4096 + j*4096 + w*512);
  };

  ffrag acc[4][4] = {};
  const int cx = (lhi ^ ((l15 ^ (l15 >> 2)) & 3)) * 8;

  stage(0, 0);
  __syncthreads();
  int cur = 0;
  for (int kt = 0; kt < 24; ++kt) {
    if (kt < 23) stage(cur ^ 1, kt + 1);
    const unsigned short* L = ldsb + cur * BUFS;
    bfrag a[2][4], b[4];
#pragma unroll
    for (int mt = 0; mt < 4; ++mt) {
      const int row = wr*64 + mt*16 + l15;
      a[0][mt] = *(const bfrag*)&L[row*32 + cx];
      a[1][mt] = *(const bfrag*)&L[4096 + row*32 + cx];
    }
#pragma unroll
    for (int nt = 0; nt < 4; ++nt) {
      const int row = wc*64 + nt*16 + l15;
      b[nt] = *(const bfrag*)&L[2*4096 + row*32 + cx];
    }
#pragma unroll
    for (int mt = 0; mt < 4; ++mt)
#pragma unroll
      for (int nt = 0; nt < 4; ++nt) {
        acc[mt][nt] = mfma16(a[0][mt], b[nt], acc[mt][nt]);
        acc[mt][nt] = mfma16(a[1][mt], b[nt], acc[mt][nt]);
      }
    __syncthreads();
    cur ^= 1;
  }

  float* fl = (float*)ldsb;
#pragma unroll
  for (int p = 0; p < 4; ++p) {
    __syncthreads();
#pragma unroll
    for (int nt = 0; nt < 4; ++nt)
#pragma unroll
      for (int q = 0; q < 4; ++q)
        fl[(wr*16 + lhi*4 + q)*BLS + wc*64 + nt*16 + l15] = acc[p][nt][q];
    __syncthreads();
    for (int i = tid; i < 2048; i += 512) {
      const int srow = i >> 6;
      const int cc   = (i & 63) << 2;
      f4 v = *(const f4*)&fl[srow*BLS + cc];
      const long grow = r0 + (srow >> 4)*64 + p*16 + (srow & 15);
      const long gcol = bc0 + cc;
      const long go = grow * Hn + gcol;
      s4v ra = *(const s4v*)&res[go];
      s4v rb2 = *(const s4v*)&res[go + (long)16384*Hn];
#pragma unroll
      for (int j = 0; j < 4; ++j)
        v[j] += bf2f(((unsigned short*)&ra)[j]) + bf2f(((unsigned short*)&rb2)[j]);
      s4v ov;
#pragma unroll
      for (int j = 0; j < 4; ++j) ((unsigned short*)&ov)[j] = f2bf(v[j]);
      *(s4v*)&outb[go] = ov;
    }
  }
}

// ---------------------------------------------------------------------------
// k_uz: u = xn@Bm^T (dup both halves) AND z = xn@gw^T. 128x128 tile, 4 waves,
// 2-buf (A=xn, B0=Bm, B1=gw staged; 48KB). Round-12 proven (86us). grid 768.
__global__ __launch_bounds__(256) void k_uz(
    const unsigned short* __restrict__ xn, const unsigned short* __restrict__ Bmb,
    const unsigned short* __restrict__ gwb,
    unsigned short* __restrict__ u, unsigned short* __restrict__ z) {
  __shared__ __align__(16) unsigned short ldsb[2 * 3 * 4096];

  const int tid = threadIdx.x, lane = tid & 63, w = tid >> 6;
  const int l15 = lane & 15, lhi = lane >> 4;
  const int wr = w >> 1, wc = w & 1;

  const int nwg = gridDim.x;
  const int q8 = nwg >> 3, r8 = nwg & 7, xcd = blockIdx.x & 7, fo = blockIdx.x >> 3;
  const int wg = (xcd < r8 ? xcd*(q8+1) : r8*(q8+1) + (xcd - r8)*q8) + fo;
  const int cb = wg % 6, rbk = wg / 6;
  const long r0 = (long)rbk * 128;
  const long bc0 = (long)cb * 128;

  const int rowin = lane >> 2, ch = lane & 3;
  long gA[2]; long gB[2]; int lbase[2];
#pragma unroll
  for (int jj = 0; jj < 2; ++jj) {
    const int inst = w*2 + jj;
    const int r = inst*16 + rowin;
    const int c = ch ^ ((r ^ (r >> 2)) & 3);
    lbase[jj] = inst * 512;
    gA[jj] = (r0 + r) * Hn + c*8;
    gB[jj] = (bc0 + r) * Hn + c*8;
  }

  auto stage = [&](int buf, int kt) {
    const int ko = kt * 32;
    unsigned short* dst = ldsb + buf * 12288;
#pragma unroll
    for (int jj = 0; jj < 2; ++jj) {
      glds16(xn  + gA[jj] + ko, dst + 0*4096 + lbase[jj]);
      glds16(Bmb + gB[jj] + ko, dst + 1*4096 + lbase[jj]);
      glds16(gwb + gB[jj] + ko, dst + 2*4096 + lbase[jj]);
    }
  };

  ffrag acc[4][4] = {};
  ffrag accZ[4][4] = {};
  const int cx = (lhi ^ ((l15 ^ (l15 >> 2)) & 3)) * 8;

  stage(0, 0);
  __syncthreads();
  int cur = 0;
  for (int kt = 0; kt < 24; ++kt) {
    if (kt < 23) stage(cur ^ 1, kt + 1);
    const unsigned short* L = ldsb + cur * 12288;
    bfrag a[4], b0[4], b1[4];
#pragma unroll
    for (int mt = 0; mt < 4; ++mt)
      a[mt] = *(const bfrag*)&L[(wr*64 + mt*16 + l15)*32 + cx];
#pragma unroll
    for (int nt = 0; nt < 4; ++nt) {
      const int row = wc*64 + nt*16 + l15;
      b0[nt] = *(const bfrag*)&L[1*4096 + row*32 + cx];
      b1[nt] = *(const bfrag*)&L[2*4096 + row*32 + cx];
    }
#pragma unroll
    for (int mt = 0; mt < 4; ++mt)
#pragma unroll
      for (int nt = 0; nt < 4; ++nt) {
        acc[mt][nt]  = mfma16(a[mt], b0[nt], acc[mt][nt]);
        accZ[mt][nt] = mfma16(a[mt], b1[nt], accZ[mt][nt]);
      }
    __syncthreads();
    cur ^= 1;
  }

  float* fl = (float*)ldsb;
#pragma unroll
  for (int which = 0; which < 2; ++which) {
#pragma unroll
    for (int hh = 0; hh < 2; ++hh) {
      __syncthreads();
      if (wr == hh) {
#pragma unroll
        for (int mt = 0; mt < 4; ++mt)
#pragma unroll
          for (int nt = 0; nt < 4; ++nt)
#pragma unroll
            for (int q = 0; q < 4; ++q)
              fl[(mt*16 + lhi*4 + q)*FLS + wc*64 + nt*16 + l15] =
                  which ? accZ[mt][nt][q] : acc[mt][nt][q];
      }
      __syncthreads();
      for (int i = tid; i < 2048; i += 256) {
        const int row = i >> 5;
        const int cc  = (i & 31) << 2;
        f4 v = *(const f4*)&fl[row*FLS + cc];
        const long go = (r0 + hh*64 + row) * Hn + bc0 + cc;
        s4v ov;
#pragma unroll
        for (int j = 0; j < 4; ++j) ((unsigned short*)&ov)[j] = f2bf(v[j]);
        if (which == 0) {
          *(s4v*)&u[go] = ov;
          *(s4v*)&u[go + (long)16384*Hn] = ov;
        } else {
          *(s4v*)&z[go] = ov;
        }
      }
    }
  }
}

// ---------------------------------------------------------------------------
// k_fin2: out = x + alpha*0.5*(Xsum@Cm^T)*sigmoid(z+gb). 128x128 tile,
// 4 waves, 2-buf 32KB staging; 4-phase FLS-padded bounce (16.9KB) keeps
// smem at 32KB -> 5 blocks/CU. grid 768. rows = t*8+b.
__global__ __launch_bounds__(256) void k_fin2(
    const unsigned short* __restrict__ A0s, const unsigned short* __restrict__ B0s,
    const unsigned short* __restrict__ z,
    const float* __restrict__ gb, const float* __restrict__ alpha,
    const float* __restrict__ x, float* __restrict__ outf) {
  __shared__ __align__(16) unsigned short ldsb[2 * 8192];   // 32 KB

  const int tid = threadIdx.x, lane = tid & 63, w = tid >> 6;
  const int l15 = lane & 15, lhi = lane >> 4;
  const int wr = w >> 1, wc = w & 1;

  const int nwg = gridDim.x;
  const int q8 = nwg >> 3, r8 = nwg & 7, xcd = blockIdx.x & 7, fo = blockIdx.x >> 3;
  const int wg = (xcd < r8 ? xcd*(q8+1) : r8*(q8+1) + (xcd - r8)*q8) + fo;
  const int cb = wg % 6, rbk = wg / 6;
  const long r0 = (long)rbk * 128;
  const long bc0 = (long)cb * 128;

  const int rowin = lane >> 2, ch = lane & 3;
  long gA[2]; long gB[2]; int lbase[2];
#pragma unroll
  for (int jj = 0; jj < 2; ++jj) {
    const int inst = w*2 + jj;
    const int r = inst*16 + rowin;
    const int c = ch ^ ((r ^ (r >> 2)) & 3);
    lbase[jj] = inst * 512;
    gA[jj] = (r0 + r) * Hn + c*8;
    gB[jj] = (bc0 + r) * Hn + c*8;
  }

  auto stage = [&](int buf, int kt) {
    const int ko = kt * 32;
    unsigned short* dst = ldsb + buf * 8192;
#pragma unroll
    for (int jj = 0; jj < 2; ++jj) {
      glds16(A0s + gA[jj] + ko, dst + lbase[jj]);
      glds16(B0s + gB[jj] + ko, dst + 4096 + lbase[jj]);
    }
  };

  ffrag acc[4][4] = {};
  const int cx = (lhi ^ ((l15 ^ (l15 >> 2)) & 3)) * 8;

  stage(0, 0);
  __syncthreads();
  int cur = 0;
  for (int kt = 0; kt < 24; ++kt) {
    if (kt < 23) stage(cur ^ 1, kt + 1);
    const unsigned short* L = ldsb + cur * 8192;
    bfrag a[4], b[4];
#pragma unroll
    for (int mt = 0; mt < 4; ++mt)
      a[mt] = *(const bfrag*)&L[(wr*64 + mt*16 + l15)*32 + cx];
#pragma unroll
    for (int nt = 0; nt < 4; ++nt)
      b[nt] = *(const bfrag*)&L[4096 + (wc*64 + nt*16 + l15)*32 + cx];
#pragma unroll
    for (int mt = 0; mt < 4; ++mt)
#pragma unroll
      for (int nt = 0; nt < 4; ++nt)
        acc[mt][nt] = mfma16(a[mt], b[nt], acc[mt][nt]);
    __syncthreads();
    cur ^= 1;
  }

  const float al = alpha[0];
  float* fl = (float*)ldsb;
#pragma unroll
  for (int p = 0; p < 4; ++p) {
    __syncthreads();
    if (wr == (p >> 1)) {
#pragma unroll
      for (int mt2 = 0; mt2 < 2; ++mt2) {
        const int mt = (p & 1)*2 + mt2;
#pragma unroll
        for (int nt = 0; nt < 4; ++nt)
#pragma unroll
          for (int q = 0; q < 4; ++q)
            fl[(mt2*16 + lhi*4 + q)*FLS + wc*64 + nt*16 + l15] = acc[mt][nt][q];
      }
    }
    __syncthreads();
    for (int i = tid; i < 1024; i += 256) {
      const int row = i >> 5;
      const int cc  = (i & 31) << 2;
      f4 v = *(const f4*)&fl[row*FLS + cc];
      const long grow = r0 + p*32 + row;
      const long gcol = bc0 + cc;
      const long go = grow * Hn + gcol;
      s4v zv = *(const s4v*)&z[go];
      f4 gbv = *(const f4*)&gb[gcol];
      const long t = grow >> 3, b = grow & 7;
      const long o = (b*2048 + t)*Hn + gcol;
      f4 xv = *(const f4*)&x[o];
      f4 ov;
#pragma unroll
      for (int j = 0; j < 4; ++j) {
        float zz = bf2f(((unsigned short*)&zv)[j]) + gbv[j];
        float g = 1.0f / (1.0f + __expf(-zz));
        ov[j] = xv[j] + al * 0.5f * v[j] * g;
      }
      *(f4*)&outf[o] = ov;
    }
  }
}

// ---------------------------------------------------------------------------
extern "C" void kernel_launch(void* const* d_in, const int* in_sizes, int n_in,
                              void* d_out, int out_size, void* d_ws, size_t ws_size,
                              hipStream_t stream) {
  const float* x     = (const float*)d_in[0];
  const float* scale = (const float*)d_in[1];
  const float* U     = (const float*)d_in[2];
  const float* V     = (const float*)d_in[3];
  const float* S     = (const float*)d_in[4];
  const float* Bm    = (const float*)d_in[5];
  const float* Cm    = (const float*)d_in[6];
  const float* gw    = (const float*)d_in[7];
  const float* gb    = (const float*)d_in[8];
  const float* alpha = (const float*)d_in[9];
  float* out = (float*)d_out;

  char* p = (char*)d_ws;
  auto alloc = [&](size_t sz) { char* r = p; p += (sz + 255) & ~(size_t)255; return r; };

  const size_t SZ_X  = (size_t)32768 * Hn * sizeof(unsigned short);  // 50.3MB
  const size_t SZ_BF = (size_t)16384 * Hn * sizeof(unsigned short);  // 25.2MB
  const size_t SZ_M  = (size_t)Hn * Hn * sizeof(float);              // 2.36MB
  const size_t SZ_MB = (size_t)Hn * Hn * sizeof(unsigned short);     // 1.18MB

  unsigned short* xn   = (unsigned short*)alloc(SZ_BF);
  unsigned short* zbuf = (unsigned short*)alloc(SZ_BF);
  unsigned short* XA = (unsigned short*)alloc(SZ_X);
  unsigned short* XB = (unsigned short*)alloc(SZ_X);
  float* Af  = (float*)alloc(SZ_M);
  float* AfT = (float*)alloc(SZ_M);
  float* P1  = (float*)alloc(SZ_M);
  float* P1T = (float*)alloc(SZ_M);
  float* P2  = (float*)alloc(SZ_M);
  float* P2T = (float*)alloc(SZ_M);
  unsigned short* Abf = (unsigned short*)alloc(SZ_MB);
  unsigned short* Ab[10];                      // A^2..A^1024 bf16
  for (int i = 0; i < 10; ++i) Ab[i] = (unsigned short*)alloc(SZ_MB);
  unsigned short* Bmb = (unsigned short*)alloc(SZ_MB);
  unsigned short* Cmb = (unsigned short*)alloc(SZ_MB);
  unsigned short* gwb = (unsigned short*)alloc(SZ_MB);
  unsigned short* zp  = (unsigned short*)alloc(1024 * sizeof(unsigned short));

  if ((size_t)(p - (char*)d_ws) > ws_size) return;  // workspace too small

  k_abuild<<<dim3(768, 4), 256, 0, stream>>>(U, V, S, Bm, Cm, gw,
      Af, AfT, Abf, Bmb, Cmb, gwb, zp);
  k_rms<<<4096, 256, 0, stream>>>(x, scale, xn);

  // squaring chain: A -> A^2 -> ... -> A^1024 (bf16 emitted each step)
  const float* sx = Af; const float* sxt = AfT;
  float* za = P1; float* zat = P1T; float* zb = P2; float* zbt = P2T;
  for (int i = 0; i < 10; ++i) {
    k_sq<<<dim3(12, 6), 512, 0, stream>>>(sx, sxt, za, zat, Ab[i]);
    sx = za; sxt = zat;
    float* t1 = za; float* t2 = zat; za = zb; zat = zbt; zb = t1; zbt = t2;
  }

  // u = xn@Bm^T (dup) + z = xn@gw^T
  k_uz<<<768, 256, 0, stream>>>(xn, Bmb, gwb, XA, zbuf);

  // doubling levels k=1..512 (shift sh=8k rows)
  unsigned short* src = XA; unsigned short* dst = XB;
  for (int i = 0; i < 10; ++i) {
    const unsigned short* W = (i == 0) ? Abf : Ab[i-1];
    k_lvl<<<1536, 256, 0, stream>>>(src, W, src, dst, zp, 8 << i);
    unsigned short* t = src; src = dst; dst = t;
  }
  // src = XA holds X_1024 (both dirs). Combine (k=1024) + fwd/bwd sum -> XB:
  k_cmb<<<384, 512, 0, stream>>>(src, Ab[9], src, XB, zp, 8192);

  // out = x + alpha*0.5*(Xsum@Cm^T)*sigmoid(z+gb)
  k_fin2<<<768, 256, 0, stream>>>(XB, Cmb, zbuf, gb, alpha, x, out);
}